// Round 1
// baseline (381.139 us; speedup 1.0000x reference)
//
#include <hip/hip_runtime.h>
#include <cstdint>

// Problem constants
constexpr int B  = 256;
constexpr int W  = 256;
constexpr int F  = 256;
constexpr int H  = 4;
constexpr int D  = 8;
constexpr int HD = H * D;   // 32
#define NEG_SLOPE 0.2f

// ---------------------------------------------------------------------------
// Kernel A: feat[b,f,o] = sum_w x[b,w,f] * fc_w[o,w]
//           el[b,h,f]   = sum_d feat[b,f,h,d] * attn_l[h,d]
//           er[b,h,f]   = sum_d feat[b,f,h,d] * attn_r[h,d]
// grid = B, block = 256 (thread = f). x reads coalesced (lane = f contiguous).
// fc_w / attn_* addresses are wave-uniform -> compiler emits scalar loads.
// ---------------------------------------------------------------------------
__global__ __launch_bounds__(256) void k_feat(
    const float* __restrict__ x, const float* __restrict__ fc_w,
    const float* __restrict__ attn_l, const float* __restrict__ attn_r,
    float* __restrict__ feat, float* __restrict__ el, float* __restrict__ er)
{
    const int b = blockIdx.x;
    const int f = threadIdx.x;
    const float* xb = x + (size_t)b * W * F + f;

    float acc[HD];
#pragma unroll
    for (int o = 0; o < HD; ++o) acc[o] = 0.f;

    for (int w = 0; w < W; w += 8) {
        float xv[8];
#pragma unroll
        for (int j = 0; j < 8; ++j) xv[j] = xb[(size_t)(w + j) * F];
#pragma unroll
        for (int o = 0; o < HD; ++o) {
            float a = acc[o];
#pragma unroll
            for (int j = 0; j < 8; ++j)
                a = fmaf(fc_w[o * W + w + j], xv[j], a);
            acc[o] = a;
        }
    }

    // attention scores per head
    float elv[H], erv[H];
#pragma unroll
    for (int h = 0; h < H; ++h) {
        float sl = 0.f, sr = 0.f;
#pragma unroll
        for (int d = 0; d < D; ++d) {
            sl = fmaf(acc[h * D + d], attn_l[h * D + d], sl);
            sr = fmaf(acc[h * D + d], attn_r[h * D + d], sr);
        }
        elv[h] = sl;
        erv[h] = sr;
    }

    float* fr = feat + ((size_t)b * F + f) * HD;
#pragma unroll
    for (int o = 0; o < HD; o += 4) {
        float4 v = make_float4(acc[o], acc[o + 1], acc[o + 2], acc[o + 3]);
        *(float4*)(fr + o) = v;
    }
#pragma unroll
    for (int h = 0; h < H; ++h) {
        el[((size_t)b * H + h) * F + f] = elv[h];
        er[((size_t)b * H + h) * F + f] = erv[h];
    }
}

// ---------------------------------------------------------------------------
// Kernel B: edge softmax + aggregation for one (b, h).
//   p[i,s] = exp(leaky_relu(el[s] + er[i]))   (no max-sub; logits are small)
//          = (el[s]+er[i] > 0) ? e^el[s]*e^er[i] : e^{.2 el[s]}*e^{.2 er[i]}
//   gout[b,i,h,:] = (sum_s p*feat[s,h,:]) / (sum_s p) + gat_bias[h,:]
// grid = (H, B), block = 128, each thread owns dst rows {t, t+128} so each
// broadcast LDS row read serves 16 FMAs.
// LDS row: [feat d0..d7, el_raw, e^el, e^{.2 el}, pad] = 48 B (16B aligned).
// ---------------------------------------------------------------------------
__global__ __launch_bounds__(128) void k_attn(
    const float* __restrict__ feat, const float* __restrict__ el,
    const float* __restrict__ er, const float* __restrict__ gat_bias,
    float* __restrict__ gout)
{
    const int h = blockIdx.x;
    const int b = blockIdx.y;
    const int t = threadIdx.x;

    __shared__ float row[F][12];

#pragma unroll
    for (int k = 0; k < 2; ++k) {
        const int s = t + k * 128;
        const float4* fp = (const float4*)(feat + ((size_t)b * F + s) * HD + h * D);
        float4 a0 = fp[0];
        float4 a1 = fp[1];
        float ev = el[((size_t)b * H + h) * F + s];
        *(float4*)&row[s][0] = a0;
        *(float4*)&row[s][4] = a1;
        row[s][8]  = ev;
        row[s][9]  = expf(ev);
        row[s][10] = expf(NEG_SLOPE * ev);
        row[s][11] = 0.f;
    }

    const int i0 = t, i1 = t + 128;
    const float er0 = er[((size_t)b * H + h) * F + i0];
    const float er1 = er[((size_t)b * H + h) * F + i1];
    const float erp0 = expf(er0), ern0 = expf(NEG_SLOPE * er0);
    const float erp1 = expf(er1), ern1 = expf(NEG_SLOPE * er1);

    __syncthreads();

    float sum0 = 0.f, sum1 = 0.f;
    float acc0[D], acc1[D];
#pragma unroll
    for (int d = 0; d < D; ++d) { acc0[d] = 0.f; acc1[d] = 0.f; }

    for (int s = 0; s < F; ++s) {
        const float4 f0 = *(const float4*)&row[s][0];
        const float4 f1 = *(const float4*)&row[s][4];
        const float4 e4 = *(const float4*)&row[s][8];  // {raw, e^el, e^.2el, pad}

        const float v0 = e4.x + er0;
        const float p0 = (v0 > 0.f) ? e4.y * erp0 : e4.z * ern0;
        const float v1 = e4.x + er1;
        const float p1 = (v1 > 0.f) ? e4.y * erp1 : e4.z * ern1;

        sum0 += p0; sum1 += p1;

        acc0[0] = fmaf(p0, f0.x, acc0[0]);
        acc0[1] = fmaf(p0, f0.y, acc0[1]);
        acc0[2] = fmaf(p0, f0.z, acc0[2]);
        acc0[3] = fmaf(p0, f0.w, acc0[3]);
        acc0[4] = fmaf(p0, f1.x, acc0[4]);
        acc0[5] = fmaf(p0, f1.y, acc0[5]);
        acc0[6] = fmaf(p0, f1.z, acc0[6]);
        acc0[7] = fmaf(p0, f1.w, acc0[7]);

        acc1[0] = fmaf(p1, f0.x, acc1[0]);
        acc1[1] = fmaf(p1, f0.y, acc1[1]);
        acc1[2] = fmaf(p1, f0.z, acc1[2]);
        acc1[3] = fmaf(p1, f0.w, acc1[3]);
        acc1[4] = fmaf(p1, f1.x, acc1[4]);
        acc1[5] = fmaf(p1, f1.y, acc1[5]);
        acc1[6] = fmaf(p1, f1.z, acc1[6]);
        acc1[7] = fmaf(p1, f1.w, acc1[7]);
    }

    const float inv0 = 1.f / sum0;
    const float inv1 = 1.f / sum1;

    float* g0 = gout + ((size_t)b * F + i0) * HD + h * D;
    float* g1 = gout + ((size_t)b * F + i1) * HD + h * D;
    float4 o00 = make_float4(fmaf(acc0[0], inv0, gat_bias[h * D + 0]),
                             fmaf(acc0[1], inv0, gat_bias[h * D + 1]),
                             fmaf(acc0[2], inv0, gat_bias[h * D + 2]),
                             fmaf(acc0[3], inv0, gat_bias[h * D + 3]));
    float4 o01 = make_float4(fmaf(acc0[4], inv0, gat_bias[h * D + 4]),
                             fmaf(acc0[5], inv0, gat_bias[h * D + 5]),
                             fmaf(acc0[6], inv0, gat_bias[h * D + 6]),
                             fmaf(acc0[7], inv0, gat_bias[h * D + 7]));
    float4 o10 = make_float4(fmaf(acc1[0], inv1, gat_bias[h * D + 0]),
                             fmaf(acc1[1], inv1, gat_bias[h * D + 1]),
                             fmaf(acc1[2], inv1, gat_bias[h * D + 2]),
                             fmaf(acc1[3], inv1, gat_bias[h * D + 3]));
    float4 o11 = make_float4(fmaf(acc1[4], inv1, gat_bias[h * D + 4]),
                             fmaf(acc1[5], inv1, gat_bias[h * D + 5]),
                             fmaf(acc1[6], inv1, gat_bias[h * D + 6]),
                             fmaf(acc1[7], inv1, gat_bias[h * D + 7]));
    *(float4*)(g0 + 0) = o00;
    *(float4*)(g0 + 4) = o01;
    *(float4*)(g1 + 0) = o10;
    *(float4*)(g1 + 4) = o11;
}

// ---------------------------------------------------------------------------
// Kernel C: out[b,w,f] = sum_o gout[b,f,o]*proj_w[w,o] + proj_b[w]
// grid = B, block = 256 (thread = f). Own gout row held in 32 VGPRs;
// proj_w/proj_b wave-uniform -> scalar loads; stores coalesced over f.
// ---------------------------------------------------------------------------
__global__ __launch_bounds__(256) void k_proj(
    const float* __restrict__ gout, const float* __restrict__ proj_w,
    const float* __restrict__ proj_b, float* __restrict__ out)
{
    const int b = blockIdx.x;
    const int f = threadIdx.x;

    float g[HD];
    const float4* gp = (const float4*)(gout + ((size_t)b * F + f) * HD);
#pragma unroll
    for (int o = 0; o < HD; o += 4) {
        float4 v = gp[o / 4];
        g[o] = v.x; g[o + 1] = v.y; g[o + 2] = v.z; g[o + 3] = v.w;
    }

    float* ob = out + (size_t)b * W * F + f;
    for (int w = 0; w < W; w += 2) {
        float a0 = proj_b[w];
        float a1 = proj_b[w + 1];
#pragma unroll
        for (int o = 0; o < HD; ++o) {
            a0 = fmaf(g[o], proj_w[w * HD + o], a0);
            a1 = fmaf(g[o], proj_w[(w + 1) * HD + o], a1);
        }
        ob[(size_t)w * F]       = a0;
        ob[(size_t)(w + 1) * F] = a1;
    }
}

// ---------------------------------------------------------------------------
extern "C" void kernel_launch(void* const* d_in, const int* in_sizes, int n_in,
                              void* d_out, int out_size, void* d_ws, size_t ws_size,
                              hipStream_t stream)
{
    const float* x      = (const float*)d_in[0];
    const float* fc_w   = (const float*)d_in[1];
    const float* attn_l = (const float*)d_in[2];
    const float* attn_r = (const float*)d_in[3];
    const float* gbias  = (const float*)d_in[4];
    const float* proj_w = (const float*)d_in[5];
    const float* proj_b = (const float*)d_in[6];
    float* out = (float*)d_out;

    // workspace layout (floats): feat[B*F*32] | el[B*H*F] | er[B*H*F] | gout[B*F*32]
    float* feat = (float*)d_ws;
    float* el   = feat + (size_t)B * F * HD;
    float* er   = el   + (size_t)B * H * F;
    float* gout = er   + (size_t)B * H * F;

    k_feat<<<B, 256, 0, stream>>>(x, fc_w, attn_l, attn_r, feat, el, er);
    k_attn<<<dim3(H, B), 128, 0, stream>>>(feat, el, er, gbias, gout);
    k_proj<<<B, 256, 0, stream>>>(gout, proj_w, proj_b, out);
}

// Round 2
// 209.884 us; speedup vs baseline: 1.8160x; 1.8160x over previous
//
#include <hip/hip_runtime.h>
#include <cstdint>

// Problem constants
constexpr int B  = 256;
constexpr int W  = 256;
constexpr int F  = 256;
constexpr int H  = 4;
constexpr int D  = 8;
constexpr int HD = H * D;   // 32
#define NEG_SLOPE 0.2f

// ---------------------------------------------------------------------------
// Kernel A: feat[b,f,o] = sum_w x[b,w,f] * fc_w[o,w]
//           el[b,h,f]   = sum_d feat[b,f,h,d] * attn_l[h,d]
//           er[b,h,f]   = sum_d feat[b,f,h,d] * attn_r[h,d]
// grid = (B, 2): blockIdx.y = og selects heads {2og, 2og+1}.
// block = 256: fp = t&127 -> f pair {2fp, 2fp+1}; oq = t>>7 -> head 2og+oq.
// Each thread owns one full head (D=8) for 2 f-columns, so el/er need no
// cross-thread reduction. float2 x loads (512B/wave), 16-deep w prefetch.
// 512 blocks -> 2 blocks/CU -> 8 waves/CU.
// ---------------------------------------------------------------------------
__global__ __launch_bounds__(256) void k_feat(
    const float* __restrict__ x, const float* __restrict__ fc_w,
    const float* __restrict__ attn_l, const float* __restrict__ attn_r,
    float* __restrict__ feat, float* __restrict__ el, float* __restrict__ er)
{
    const int b  = blockIdx.x;
    const int og = blockIdx.y;           // 0..1
    const int t  = threadIdx.x;
    const int fp = t & 127;
    const int oq = t >> 7;               // 0..1 (wave-uniform)
    const int f0 = fp * 2;
    const int h  = og * 2 + oq;          // head 0..3
    const int obase = __builtin_amdgcn_readfirstlane(h * D);

    const float* xb = x + (size_t)b * W * F + f0;
    const float* fw = fc_w + (size_t)obase * W;   // 8 rows of length W

    float acc0[D], acc1[D];
#pragma unroll
    for (int o = 0; o < D; ++o) { acc0[o] = 0.f; acc1[o] = 0.f; }

    constexpr int WS = 16;
    float2 cur[WS], nxt[WS];
#pragma unroll
    for (int j = 0; j < WS; ++j) cur[j] = *(const float2*)(xb + (size_t)j * F);

    for (int w = 0; w < W; w += WS) {
        if (w + WS < W) {
#pragma unroll
            for (int j = 0; j < WS; ++j)
                nxt[j] = *(const float2*)(xb + (size_t)(w + WS + j) * F);
        }
#pragma unroll
        for (int o = 0; o < D; ++o) {
            float a0 = acc0[o], a1 = acc1[o];
#pragma unroll
            for (int j = 0; j < WS; ++j) {
                const float c = fw[o * W + w + j];
                a0 = fmaf(c, cur[j].x, a0);
                a1 = fmaf(c, cur[j].y, a1);
            }
            acc0[o] = a0; acc1[o] = a1;
        }
#pragma unroll
        for (int j = 0; j < WS; ++j) cur[j] = nxt[j];
    }

    // attention scores for head h, both f columns
    float el0 = 0.f, er0 = 0.f, el1 = 0.f, er1 = 0.f;
#pragma unroll
    for (int d = 0; d < D; ++d) {
        const float al = attn_l[obase + d];
        const float ar = attn_r[obase + d];
        el0 = fmaf(acc0[d], al, el0);
        er0 = fmaf(acc0[d], ar, er0);
        el1 = fmaf(acc1[d], al, el1);
        er1 = fmaf(acc1[d], ar, er1);
    }

    float* fr0 = feat + ((size_t)b * F + f0) * HD + obase;
    float* fr1 = fr0 + HD;
    *(float4*)(fr0 + 0) = make_float4(acc0[0], acc0[1], acc0[2], acc0[3]);
    *(float4*)(fr0 + 4) = make_float4(acc0[4], acc0[5], acc0[6], acc0[7]);
    *(float4*)(fr1 + 0) = make_float4(acc1[0], acc1[1], acc1[2], acc1[3]);
    *(float4*)(fr1 + 4) = make_float4(acc1[4], acc1[5], acc1[6], acc1[7]);

    *(float2*)(el + ((size_t)b * H + h) * F + f0) = make_float2(el0, el1);
    *(float2*)(er + ((size_t)b * H + h) * F + f0) = make_float2(er0, er1);
}

// ---------------------------------------------------------------------------
// Kernel B: edge softmax + aggregation for one (b, h).
//   p[i,s] = exp(leaky_relu(el[s] + er[i]))
//          = (el[s]+er[i] > 0) ? e^el[s]*e^er[i] : e^{.2 el[s]}*e^{.2 er[i]}
// block = 256: i = t&127 -> dst rows {i, i+128}; sh = t>>7 -> src half.
// Each thread accumulates over 128 src; halves combined through LDS.
// grid = (H, B) = 1024 blocks -> 4 blocks/CU -> 16 waves/CU.
// ---------------------------------------------------------------------------
__global__ __launch_bounds__(256) void k_attn(
    const float* __restrict__ feat, const float* __restrict__ el,
    const float* __restrict__ er, const float* __restrict__ gat_bias,
    float* __restrict__ gout)
{
    const int h = blockIdx.x;
    const int b = blockIdx.y;
    const int t = threadIdx.x;
    const int i = t & 127;
    const int sh = t >> 7;

    __shared__ float row[F][12];
    __shared__ float red[128][20];

    // stage one src row per thread
    {
        const int s = t;
        const float4* fp = (const float4*)(feat + ((size_t)b * F + s) * HD + h * D);
        float4 a0 = fp[0];
        float4 a1 = fp[1];
        float ev = el[((size_t)b * H + h) * F + s];
        *(float4*)&row[s][0] = a0;
        *(float4*)&row[s][4] = a1;
        row[s][8]  = ev;
        row[s][9]  = expf(ev);
        row[s][10] = expf(NEG_SLOPE * ev);
        row[s][11] = 0.f;
    }

    const int i0 = i, i1 = i + 128;
    const float er0 = er[((size_t)b * H + h) * F + i0];
    const float er1 = er[((size_t)b * H + h) * F + i1];
    const float erp0 = expf(er0), ern0 = expf(NEG_SLOPE * er0);
    const float erp1 = expf(er1), ern1 = expf(NEG_SLOPE * er1);

    __syncthreads();

    float sum0 = 0.f, sum1 = 0.f;
    float acc0[D], acc1[D];
#pragma unroll
    for (int d = 0; d < D; ++d) { acc0[d] = 0.f; acc1[d] = 0.f; }

    const int sbeg = sh * 128, send = sbeg + 128;
    for (int s = sbeg; s < send; ++s) {
        const float4 f0 = *(const float4*)&row[s][0];
        const float4 f1 = *(const float4*)&row[s][4];
        const float4 e4 = *(const float4*)&row[s][8];  // {raw, e^el, e^.2el, pad}

        const float v0 = e4.x + er0;
        const float p0 = (v0 > 0.f) ? e4.y * erp0 : e4.z * ern0;
        const float v1 = e4.x + er1;
        const float p1 = (v1 > 0.f) ? e4.y * erp1 : e4.z * ern1;

        sum0 += p0; sum1 += p1;

        acc0[0] = fmaf(p0, f0.x, acc0[0]);
        acc0[1] = fmaf(p0, f0.y, acc0[1]);
        acc0[2] = fmaf(p0, f0.z, acc0[2]);
        acc0[3] = fmaf(p0, f0.w, acc0[3]);
        acc0[4] = fmaf(p0, f1.x, acc0[4]);
        acc0[5] = fmaf(p0, f1.y, acc0[5]);
        acc0[6] = fmaf(p0, f1.z, acc0[6]);
        acc0[7] = fmaf(p0, f1.w, acc0[7]);

        acc1[0] = fmaf(p1, f0.x, acc1[0]);
        acc1[1] = fmaf(p1, f0.y, acc1[1]);
        acc1[2] = fmaf(p1, f0.z, acc1[2]);
        acc1[3] = fmaf(p1, f0.w, acc1[3]);
        acc1[4] = fmaf(p1, f1.x, acc1[4]);
        acc1[5] = fmaf(p1, f1.y, acc1[5]);
        acc1[6] = fmaf(p1, f1.z, acc1[6]);
        acc1[7] = fmaf(p1, f1.w, acc1[7]);
    }

    // combine src halves: sh==1 publishes, sh==0 reduces + writes out
    if (sh == 1) {
        float* r = red[i];
        *(float4*)(r + 0)  = make_float4(acc0[0], acc0[1], acc0[2], acc0[3]);
        *(float4*)(r + 4)  = make_float4(acc0[4], acc0[5], acc0[6], acc0[7]);
        *(float4*)(r + 8)  = make_float4(acc1[0], acc1[1], acc1[2], acc1[3]);
        *(float4*)(r + 12) = make_float4(acc1[4], acc1[5], acc1[6], acc1[7]);
        *(float2*)(r + 16) = make_float2(sum0, sum1);
    }
    __syncthreads();
    if (sh == 0) {
        const float* r = red[i];
#pragma unroll
        for (int d = 0; d < D; ++d) {
            acc0[d] += r[d];
            acc1[d] += r[8 + d];
        }
        sum0 += r[16];
        sum1 += r[17];

        const float inv0 = 1.f / sum0;
        const float inv1 = 1.f / sum1;

        float* g0 = gout + ((size_t)b * F + i0) * HD + h * D;
        float* g1 = gout + ((size_t)b * F + i1) * HD + h * D;
        *(float4*)(g0 + 0) = make_float4(fmaf(acc0[0], inv0, gat_bias[h * D + 0]),
                                         fmaf(acc0[1], inv0, gat_bias[h * D + 1]),
                                         fmaf(acc0[2], inv0, gat_bias[h * D + 2]),
                                         fmaf(acc0[3], inv0, gat_bias[h * D + 3]));
        *(float4*)(g0 + 4) = make_float4(fmaf(acc0[4], inv0, gat_bias[h * D + 4]),
                                         fmaf(acc0[5], inv0, gat_bias[h * D + 5]),
                                         fmaf(acc0[6], inv0, gat_bias[h * D + 6]),
                                         fmaf(acc0[7], inv0, gat_bias[h * D + 7]));
        *(float4*)(g1 + 0) = make_float4(fmaf(acc1[0], inv1, gat_bias[h * D + 0]),
                                         fmaf(acc1[1], inv1, gat_bias[h * D + 1]),
                                         fmaf(acc1[2], inv1, gat_bias[h * D + 2]),
                                         fmaf(acc1[3], inv1, gat_bias[h * D + 3]));
        *(float4*)(g1 + 4) = make_float4(fmaf(acc1[4], inv1, gat_bias[h * D + 4]),
                                         fmaf(acc1[5], inv1, gat_bias[h * D + 5]),
                                         fmaf(acc1[6], inv1, gat_bias[h * D + 6]),
                                         fmaf(acc1[7], inv1, gat_bias[h * D + 7]));
    }
}

// ---------------------------------------------------------------------------
// Kernel C: out[b,w,f] = sum_o gout[b,f,o]*proj_w[w,o] + proj_b[w]
// grid = (B, 8): blockIdx.y = wq -> 32 w's per block. 2048 blocks ->
// 8 blocks/CU -> 32 waves/CU. Same-b blocks are 256 apart in linear id
// (256 % 8 == 0) -> same XCD -> gout re-reads hit L2.
// ---------------------------------------------------------------------------
__global__ __launch_bounds__(256) void k_proj(
    const float* __restrict__ gout, const float* __restrict__ proj_w,
    const float* __restrict__ proj_b, float* __restrict__ out)
{
    const int b  = blockIdx.x;
    const int wq = blockIdx.y;   // 0..7
    const int f  = threadIdx.x;

    float g[HD];
    const float4* gp = (const float4*)(gout + ((size_t)b * F + f) * HD);
#pragma unroll
    for (int o = 0; o < HD; o += 4) {
        float4 v = gp[o / 4];
        g[o] = v.x; g[o + 1] = v.y; g[o + 2] = v.z; g[o + 3] = v.w;
    }

    const int wbeg = wq * 32;
    float* ob = out + (size_t)b * W * F + f;
    for (int w = wbeg; w < wbeg + 32; w += 2) {
        float a0 = proj_b[w];
        float a1 = proj_b[w + 1];
#pragma unroll
        for (int o = 0; o < HD; ++o) {
            a0 = fmaf(g[o], proj_w[w * HD + o], a0);
            a1 = fmaf(g[o], proj_w[(w + 1) * HD + o], a1);
        }
        ob[(size_t)w * F]       = a0;
        ob[(size_t)(w + 1) * F] = a1;
    }
}

// ---------------------------------------------------------------------------
extern "C" void kernel_launch(void* const* d_in, const int* in_sizes, int n_in,
                              void* d_out, int out_size, void* d_ws, size_t ws_size,
                              hipStream_t stream)
{
    const float* x      = (const float*)d_in[0];
    const float* fc_w   = (const float*)d_in[1];
    const float* attn_l = (const float*)d_in[2];
    const float* attn_r = (const float*)d_in[3];
    const float* gbias  = (const float*)d_in[4];
    const float* proj_w = (const float*)d_in[5];
    const float* proj_b = (const float*)d_in[6];
    float* out = (float*)d_out;

    // workspace layout (floats): feat[B*F*32] | el[B*H*F] | er[B*H*F] | gout[B*F*32]
    float* feat = (float*)d_ws;
    float* el   = feat + (size_t)B * F * HD;
    float* er   = el   + (size_t)B * H * F;
    float* gout = er   + (size_t)B * H * F;

    k_feat<<<dim3(B, 2), 256, 0, stream>>>(x, fc_w, attn_l, attn_r, feat, el, er);
    k_attn<<<dim3(H, B), 256, 0, stream>>>(feat, el, er, gbias, gout);
    k_proj<<<dim3(B, 8), 256, 0, stream>>>(gout, proj_w, proj_b, out);
}